// Round 1
// baseline (243.483 us; speedup 1.0000x reference)
//
#include <hip/hip_runtime.h>
#include <stdint.h>

typedef int   int32x4 __attribute__((ext_vector_type(4)));

constexpr int K_DIM = 4096;   // D_IN
constexpr int N_DIM = 4096;   // D_OUT
constexpr float QMAXF = 127.0f;

// ---------------------------------------------------------------------------
// Kernel 1: per-token dynamic absmax quantization.
// x: [M][K] float32 (fp16-valued). One block (256 thr) per row.
// Writes q [M][K] int8 and scales[M] float.
// ---------------------------------------------------------------------------
__global__ __launch_bounds__(256) void quant_rows(const float* __restrict__ x,
                                                  int8_t* __restrict__ q,
                                                  float* __restrict__ scales) {
    const int row = blockIdx.x;
    const int tid = threadIdx.x;
    const size_t base = (size_t)row * K_DIM;

    const float4* xv = reinterpret_cast<const float4*>(x + base);
    float4 v[4];
#pragma unroll
    for (int i = 0; i < 4; ++i) v[i] = xv[tid + 256 * i];

    float m = 0.0f;
#pragma unroll
    for (int i = 0; i < 4; ++i) {
        m = fmaxf(m, fmaxf(fmaxf(fabsf(v[i].x), fabsf(v[i].y)),
                           fmaxf(fabsf(v[i].z), fabsf(v[i].w))));
    }
#pragma unroll
    for (int off = 32; off > 0; off >>= 1) m = fmaxf(m, __shfl_xor(m, off));

    __shared__ float wmax[4];
    if ((tid & 63) == 0) wmax[tid >> 6] = m;
    __syncthreads();
    const float am = fmaxf(fmaxf(wmax[0], wmax[1]), fmaxf(wmax[2], wmax[3]));
    const float scale = fmaxf(am * (1.0f / 127.0f), 1e-8f);
    if (tid == 0) scales[row] = scale;
    const float inv = 1.0f / scale;

    int* qw = reinterpret_cast<int*>(q + base);
#pragma unroll
    for (int i = 0; i < 4; ++i) {
        float f0 = fminf(QMAXF, fmaxf(-QMAXF, rintf(v[i].x * inv)));
        float f1 = fminf(QMAXF, fmaxf(-QMAXF, rintf(v[i].y * inv)));
        float f2 = fminf(QMAXF, fmaxf(-QMAXF, rintf(v[i].z * inv)));
        float f3 = fminf(QMAXF, fmaxf(-QMAXF, rintf(v[i].w * inv)));
        int b0 = ((int)f0) & 255, b1 = ((int)f1) & 255;
        int b2 = ((int)f2) & 255, b3 = ((int)f3) & 255;
        qw[tid + 256 * i] = b0 | (b1 << 8) | (b2 << 16) | (b3 << 24);
    }
}

// ---------------------------------------------------------------------------
// Kernel 2: pack int32 weight buffer -> int8.
// ---------------------------------------------------------------------------
__global__ __launch_bounds__(256) void pack_w(const int* __restrict__ w,
                                              int8_t* __restrict__ w8) {
    const int idx = blockIdx.x * 256 + threadIdx.x;     // handles 4 elements
    const int4 v = reinterpret_cast<const int4*>(w)[idx];
    int packed = (v.x & 255) | ((v.y & 255) << 8) | ((v.z & 255) << 16) | ((v.w & 255) << 24);
    reinterpret_cast<int*>(w8)[idx] = packed;
}

// ---------------------------------------------------------------------------
// Kernel 3: int8 GEMM, m97 structure (128x128 tile, BK=64, 4 waves, 2x2 wave
// grid, global_load_lds width=16 staging, mfma_i32_16x16x64_i8), fused dequant.
// A = q [M][K] int8, B = w8 [N][K] int8 (B^T layout). C = out [M][N] float.
// ---------------------------------------------------------------------------
__global__ __launch_bounds__(256) void w8a8_gemm(const int8_t* __restrict__ A,
                                                 const int8_t* __restrict__ B,
                                                 const float* __restrict__ asc,
                                                 const float* __restrict__ wsc,
                                                 float* __restrict__ C) {
    constexpr int BK = 64;
    __shared__ __align__(16) int8_t As[128][BK];   // 8 KB
    __shared__ __align__(16) int8_t Bs[128][BK];   // 8 KB

    const int tid  = threadIdx.x;
    const int wave = tid >> 6;
    const int lane = tid & 63;

    // XCD-aware bijective swizzle (nwg = 2048, divisible by 8)
    const int nwg = gridDim.x;
    const int bid = blockIdx.x;
    const int swz = (bid & 7) * (nwg >> 3) + (bid >> 3);
    const int NB  = N_DIM / 128;         // 32
    const int brow = (swz / NB) * 128;
    const int bcol = (swz % NB) * 128;

    const int wm = (wave >> 1) * 64;     // wave's 64x64 sub-tile
    const int wn = (wave & 1) * 64;

    const int frow = lane & 15;          // fragment row/col within 16
    const int fko  = (lane >> 4) * 16;   // fragment K byte offset

    int32x4 acc[4][4];
#pragma unroll
    for (int i = 0; i < 4; ++i)
#pragma unroll
        for (int j = 0; j < 4; ++j) acc[i][j] = (int32x4){0, 0, 0, 0};

    // staging: 512 segments of 16B per tile; segment s -> row s>>2, col (s&3)*16
    const int s0 = tid, s1 = 256 + tid;
    const int8_t* gA0 = A + (size_t)(brow + (s0 >> 2)) * K_DIM + (s0 & 3) * 16;
    const int8_t* gA1 = A + (size_t)(brow + (s1 >> 2)) * K_DIM + (s1 & 3) * 16;
    const int8_t* gB0 = B + (size_t)(bcol + (s0 >> 2)) * K_DIM + (s0 & 3) * 16;
    const int8_t* gB1 = B + (size_t)(bcol + (s1 >> 2)) * K_DIM + (s1 & 3) * 16;

    // wave-uniform LDS destination bases (hardware adds lane*16)
    int8_t* lA0 = &As[0][0] + (wave * 64) * 16;
    int8_t* lA1 = &As[0][0] + (256 + wave * 64) * 16;
    int8_t* lB0 = &Bs[0][0] + (wave * 64) * 16;
    int8_t* lB1 = &Bs[0][0] + (256 + wave * 64) * 16;

    for (int kk = 0; kk < K_DIM; kk += BK) {
        __syncthreads();   // previous compute done before overwrite
        __builtin_amdgcn_global_load_lds(
            (const __attribute__((address_space(1))) unsigned int*)(gA0 + kk),
            (__attribute__((address_space(3))) unsigned int*)lA0, 16, 0, 0);
        __builtin_amdgcn_global_load_lds(
            (const __attribute__((address_space(1))) unsigned int*)(gA1 + kk),
            (__attribute__((address_space(3))) unsigned int*)lA1, 16, 0, 0);
        __builtin_amdgcn_global_load_lds(
            (const __attribute__((address_space(1))) unsigned int*)(gB0 + kk),
            (__attribute__((address_space(3))) unsigned int*)lB0, 16, 0, 0);
        __builtin_amdgcn_global_load_lds(
            (const __attribute__((address_space(1))) unsigned int*)(gB1 + kk),
            (__attribute__((address_space(3))) unsigned int*)lB1, 16, 0, 0);
        __syncthreads();   // compiler drains vmcnt before barrier

        int32x4 af[4], bf[4];
#pragma unroll
        for (int mi = 0; mi < 4; ++mi)
            af[mi] = *reinterpret_cast<const int32x4*>(&As[wm + mi * 16 + frow][fko]);
#pragma unroll
        for (int ni = 0; ni < 4; ++ni)
            bf[ni] = *reinterpret_cast<const int32x4*>(&Bs[wn + ni * 16 + frow][fko]);
#pragma unroll
        for (int mi = 0; mi < 4; ++mi)
#pragma unroll
            for (int ni = 0; ni < 4; ++ni)
                acc[mi][ni] = __builtin_amdgcn_mfma_i32_16x16x64_i8(
                    af[mi], bf[ni], acc[mi][ni], 0, 0, 0);
    }

    // epilogue: C/D layout col = lane&15, row = (lane>>4)*4 + reg (m89/m101)
    const int c0 = lane & 15;
    const int r0 = (lane >> 4) * 4;
#pragma unroll
    for (int ni = 0; ni < 4; ++ni) {
        const int col = bcol + wn + ni * 16 + c0;
        const float ws = wsc[col];
#pragma unroll
        for (int mi = 0; mi < 4; ++mi) {
            const int rowb = brow + wm + mi * 16 + r0;
#pragma unroll
            for (int r = 0; r < 4; ++r) {
                const int row = rowb + r;
                float o = (float)acc[mi][ni][r] * asc[row] * ws;
                o = (float)(_Float16)o;   // emulate reference's fp16 cast
                C[(size_t)row * N_DIM + col] = o;
            }
        }
    }
}

// ---------------------------------------------------------------------------
extern "C" void kernel_launch(void* const* d_in, const int* in_sizes, int n_in,
                              void* d_out, int out_size, void* d_ws, size_t ws_size,
                              hipStream_t stream) {
    const float* x   = (const float*)d_in[0];   // [M][K], fp16-valued f32
    const int*   w   = (const int*)d_in[1];     // [N][K] int32 (int8-valued)
    const float* wsc = (const float*)d_in[2];   // [N]
    float* out = (float*)d_out;                 // [M][N] (fp16-valued f32)

    const int K = K_DIM;
    const int M = in_sizes[0] / K;              // 8192
    const int N = N_DIM;                        // == in_sizes[2]

    int8_t* q   = (int8_t*)d_ws;                               // M*K  = 32 MB
    int8_t* w8  = (int8_t*)d_ws + (size_t)M * K;               // N*K  = 16 MB
    float*  asc = (float*)((char*)d_ws + (size_t)M * K + (size_t)N * K);

    quant_rows<<<M, 256, 0, stream>>>(x, q, asc);
    pack_w<<<(N * (K / 4)) / 256, 256, 0, stream>>>(w, w8);
    const int grid = (M / 128) * (N / 128);     // 2048
    w8a8_gemm<<<grid, 256, 0, stream>>>(q, w8, asc, wsc, out);
}

// Round 2
// 199.572 us; speedup vs baseline: 1.2200x; 1.2200x over previous
//
#include <hip/hip_runtime.h>
#include <stdint.h>

typedef int int32x4 __attribute__((ext_vector_type(4)));

constexpr int K_DIM = 4096;   // D_IN
constexpr int N_DIM = 4096;   // D_OUT
constexpr float QMAXF = 127.0f;

// ---------------------------------------------------------------------------
// Kernel 1: per-token dynamic absmax quantization (unchanged, ~8 us)
// ---------------------------------------------------------------------------
__global__ __launch_bounds__(256) void quant_rows(const float* __restrict__ x,
                                                  int8_t* __restrict__ q,
                                                  float* __restrict__ scales) {
    const int row = blockIdx.x;
    const int tid = threadIdx.x;
    const size_t base = (size_t)row * K_DIM;

    const float4* xv = reinterpret_cast<const float4*>(x + base);
    float4 v[4];
#pragma unroll
    for (int i = 0; i < 4; ++i) v[i] = xv[tid + 256 * i];

    float m = 0.0f;
#pragma unroll
    for (int i = 0; i < 4; ++i)
        m = fmaxf(m, fmaxf(fmaxf(fabsf(v[i].x), fabsf(v[i].y)),
                           fmaxf(fabsf(v[i].z), fabsf(v[i].w))));
#pragma unroll
    for (int off = 32; off > 0; off >>= 1) m = fmaxf(m, __shfl_xor(m, off));

    __shared__ float wmax[4];
    if ((tid & 63) == 0) wmax[tid >> 6] = m;
    __syncthreads();
    const float am = fmaxf(fmaxf(wmax[0], wmax[1]), fmaxf(wmax[2], wmax[3]));
    const float scale = fmaxf(am * (1.0f / 127.0f), 1e-8f);
    if (tid == 0) scales[row] = scale;
    const float inv = 1.0f / scale;

    int* qw = reinterpret_cast<int*>(q + base);
#pragma unroll
    for (int i = 0; i < 4; ++i) {
        float f0 = fminf(QMAXF, fmaxf(-QMAXF, rintf(v[i].x * inv)));
        float f1 = fminf(QMAXF, fmaxf(-QMAXF, rintf(v[i].y * inv)));
        float f2 = fminf(QMAXF, fmaxf(-QMAXF, rintf(v[i].z * inv)));
        float f3 = fminf(QMAXF, fmaxf(-QMAXF, rintf(v[i].w * inv)));
        int b0 = ((int)f0) & 255, b1 = ((int)f1) & 255;
        int b2 = ((int)f2) & 255, b3 = ((int)f3) & 255;
        qw[tid + 256 * i] = b0 | (b1 << 8) | (b2 << 16) | (b3 << 24);
    }
}

// ---------------------------------------------------------------------------
// Kernel 2: pack int32 weight buffer -> int8 (unchanged, ~3 us)
// ---------------------------------------------------------------------------
__global__ __launch_bounds__(256) void pack_w(const int* __restrict__ w,
                                              int8_t* __restrict__ w8) {
    const int idx = blockIdx.x * 256 + threadIdx.x;
    const int4 v = reinterpret_cast<const int4*>(w)[idx];
    int packed = (v.x & 255) | ((v.y & 255) << 8) | ((v.z & 255) << 16) | ((v.w & 255) << 24);
    reinterpret_cast<int*>(w8)[idx] = packed;
}

// ---------------------------------------------------------------------------
// Kernel 3: int8 GEMM, 256x256 tile, BK=64, 8 waves (2Mx4N), 4-deep LDS
// pipeline with counted vmcnt (T3+T4), XOR-swizzled LDS (T2), setprio (T5).
// A = q [M][K] int8, B = w8 [N][K] int8 (B^T layout). C = out [M][N] float.
// ---------------------------------------------------------------------------
constexpr int BM = 256, BN = 256, BK = 64;
constexpr int NT = K_DIM / BK;     // 64 K-tiles
// per-buffer per-matrix: 256*64 = 16 KB = 1024 segments of 16B

#define GLL(src, dst)                                                          \
    __builtin_amdgcn_global_load_lds(                                          \
        (const __attribute__((address_space(1))) unsigned int*)(src),          \
        (__attribute__((address_space(3))) unsigned int*)(dst), 16, 0, 0)

__global__ __launch_bounds__(512, 2) void w8a8_gemm256(
        const int8_t* __restrict__ A, const int8_t* __restrict__ B,
        const float* __restrict__ asc, const float* __restrict__ wsc,
        float* __restrict__ C, int M) {
    __shared__ int8_t As[4][BM][BK];          // 64 KB static
    extern __shared__ int8_t Bs_raw[];        // 64 KB dynamic
    int8_t* Bs = Bs_raw;                      // [4][BM][BK]

    const int tid  = threadIdx.x;
    const int lane = tid & 63;

    // XCD-aware bijective swizzle (nwg = 512, divisible by 8)
    const int nwg = gridDim.x;
    const int bid = blockIdx.x;
    const int swz = (bid & 7) * (nwg >> 3) + (bid >> 3);
    const int NB  = N_DIM / BN;               // 16
    const int brow = (swz / NB) * BM;
    const int bcol = (swz % NB) * BN;

    const int wm = (tid >> 6) >> 2;           // 0..1  (M half)
    const int wn = (tid >> 6) & 3;            // 0..3  (N quarter)

    // ---- staging: seg s -> row s>>2, LDS slot s&3, global granule (s&3)^((r>>1)&3)
    const int s0 = tid, s1 = tid + 512;
    const int r0s = s0 >> 2, g0 = (s0 & 3) ^ ((r0s >> 1) & 3);
    const int r1s = s1 >> 2, g1 = (s1 & 3) ^ ((r1s >> 1) & 3);
    const int8_t* gA0 = A + (size_t)(brow + r0s) * K_DIM + g0 * 16;
    const int8_t* gA1 = A + (size_t)(brow + r1s) * K_DIM + g1 * 16;
    const int8_t* gB0 = B + (size_t)(bcol + r0s) * K_DIM + g0 * 16;
    const int8_t* gB1 = B + (size_t)(bcol + r1s) * K_DIM + g1 * 16;
    // wave-uniform LDS seg bases (HW adds lane*16)
    const int segb0 = (tid >> 6) * 1024;      // wave*64 segs *16B
    const int segb1 = segb0 + 8192;

    // ---- compute-side swizzled LDS offsets (per lane) ----
    const int l15 = lane & 15;
    const int ls  = lane >> 4;
    const int rA  = wm * 128 + l15;                  // + mi*16
    const int offA = rA * BK + ((ls ^ ((rA >> 1) & 3)) * 16);
    const int rB  = wn * 64 + l15;                   // + ni*16
    const int offB = rB * BK + ((ls ^ ((rB >> 1) & 3)) * 16);

    int32x4 acc[8][4];
#pragma unroll
    for (int i = 0; i < 8; ++i)
#pragma unroll
        for (int j = 0; j < 4; ++j) acc[i][j] = (int32x4){0, 0, 0, 0};

    // ---- prologue: stage tiles 0,1,2 (12 loads/thread total) ----
#pragma unroll
    for (int t = 0; t < 3; ++t) {
        const size_t kk = (size_t)t * BK;
        int8_t* lA = &As[t][0][0];
        int8_t* lB = Bs + t * (BM * BK);
        GLL(gA0 + kk, lA + segb0);
        GLL(gA1 + kk, lA + segb1);
        GLL(gB0 + kk, lB + segb0);
        GLL(gB1 + kk, lB + segb1);
    }
    asm volatile("s_waitcnt vmcnt(8)" ::: "memory");   // tile 0 landed
    __builtin_amdgcn_s_barrier();

    // ---- main loop: 2 phases per K-tile, stage tile t+3 ----
    for (int t = 0; t < NT; ++t) {
        const int b = t & 3;
        const int8_t* abuf = &As[b][0][0];
        const int8_t* bbuf = Bs + b * (BM * BK);
        const int   pb  = (t + 3) & 3;
        const size_t kk = (size_t)(t + 3) * BK;
        const bool  pf  = (t + 3 < NT);

        // phase 0: prefetch A(t+3); read B frags + A frags mi 0-3; 16 MFMA
        if (pf) {
            int8_t* lA = &As[pb][0][0];
            GLL(gA0 + kk, lA + segb0);
            GLL(gA1 + kk, lA + segb1);
        }
        int32x4 bf[4], af[4];
#pragma unroll
        for (int ni = 0; ni < 4; ++ni)
            bf[ni] = *(const int32x4*)(bbuf + offB + ni * 1024);
#pragma unroll
        for (int mi = 0; mi < 4; ++mi)
            af[mi] = *(const int32x4*)(abuf + offA + mi * 1024);
        __builtin_amdgcn_s_setprio(1);
#pragma unroll
        for (int mi = 0; mi < 4; ++mi)
#pragma unroll
            for (int ni = 0; ni < 4; ++ni)
                acc[mi][ni] = __builtin_amdgcn_mfma_i32_16x16x64_i8(
                    af[mi], bf[ni], acc[mi][ni], 0, 0, 0);
        __builtin_amdgcn_s_setprio(0);
        __builtin_amdgcn_s_barrier();

        // phase 1: prefetch B(t+3); read A frags mi 4-7; 16 MFMA
        if (pf) {
            int8_t* lB = Bs + pb * (BM * BK);
            GLL(gB0 + kk, lB + segb0);
            GLL(gB1 + kk, lB + segb1);
        }
#pragma unroll
        for (int mi = 0; mi < 4; ++mi)
            af[mi] = *(const int32x4*)(abuf + offA + (mi + 4) * 1024);
        __builtin_amdgcn_s_setprio(1);
#pragma unroll
        for (int mi = 0; mi < 4; ++mi)
#pragma unroll
            for (int ni = 0; ni < 4; ++ni)
                acc[mi + 4][ni] = __builtin_amdgcn_mfma_i32_16x16x64_i8(
                    af[mi], bf[ni], acc[mi + 4][ni], 0, 0, 0);
        __builtin_amdgcn_s_setprio(0);

        // counted wait: tile t+1 (oldest 4 outstanding loads) must have landed
        if (t < NT - 3)       asm volatile("s_waitcnt vmcnt(8)" ::: "memory");
        else if (t == NT - 3) asm volatile("s_waitcnt vmcnt(4)" ::: "memory");
        else                  asm volatile("s_waitcnt vmcnt(0)" ::: "memory");
        __builtin_amdgcn_s_barrier();
    }

    // ---- epilogue: dequant + fp16-round, C/D layout col=lane&15, row=(lane>>4)*4+reg
    const int c0  = lane & 15;
    const int rr0 = (lane >> 4) * 4;
#pragma unroll
    for (int ni = 0; ni < 4; ++ni) {
        const int col = bcol + wn * 64 + ni * 16 + c0;
        const float ws = wsc[col];
#pragma unroll
        for (int mi = 0; mi < 8; ++mi) {
            const int rowb = brow + wm * 128 + mi * 16 + rr0;
#pragma unroll
            for (int r = 0; r < 4; ++r) {
                const int row = rowb + r;
                float o = (float)acc[mi][ni][r] * asc[row] * ws;
                o = (float)(_Float16)o;   // emulate reference's fp16 cast
                C[(size_t)row * N_DIM + col] = o;
            }
        }
    }
}

// ---------------------------------------------------------------------------
extern "C" void kernel_launch(void* const* d_in, const int* in_sizes, int n_in,
                              void* d_out, int out_size, void* d_ws, size_t ws_size,
                              hipStream_t stream) {
    const float* x   = (const float*)d_in[0];   // [M][K], fp16-valued f32
    const int*   w   = (const int*)d_in[1];     // [N][K] int32 (int8-valued)
    const float* wsc = (const float*)d_in[2];   // [N]
    float* out = (float*)d_out;                 // [M][N] (fp16-valued f32)

    const int K = K_DIM;
    const int M = in_sizes[0] / K;              // 8192
    const int N = N_DIM;

    int8_t* q   = (int8_t*)d_ws;                               // M*K  = 32 MB
    int8_t* w8  = (int8_t*)d_ws + (size_t)M * K;               // N*K  = 16 MB
    float*  asc = (float*)((char*)d_ws + (size_t)M * K + (size_t)N * K);

    quant_rows<<<M, 256, 0, stream>>>(x, q, asc);
    pack_w<<<(N * (K / 4)) / 256, 256, 0, stream>>>(w, w8);
    const int grid = (M / BM) * (N / BN);       // 512
    w8a8_gemm256<<<grid, 512, 65536, stream>>>(q, w8, asc, wsc, out, M);
}